// Round 1
// baseline (175.145 us; speedup 1.0000x reference)
//
#include <hip/hip_runtime.h>
#include <math.h>

#define VOCAB 100000
#define EMB   128
#define BATCH 16384
#define CTX   20
#define NEG   20

__global__ void zero_out_kernel(float* out) {
    out[0] = 0.0f;
}

// Butterfly sum over a 32-lane half-wave. xor masks < 32 never cross the
// half boundary, so lanes 0-31 and 32-63 reduce independently. All lanes
// of the half end up with the full sum.
__device__ __forceinline__ float half_wave_dot(float4 a, float4 b) {
    float p = a.x * b.x + a.y * b.y + a.z * b.z + a.w * b.w;
    p += __shfl_xor(p, 16);
    p += __shfl_xor(p, 8);
    p += __shfl_xor(p, 4);
    p += __shfl_xor(p, 2);
    p += __shfl_xor(p, 1);
    return p;
}

__global__ __launch_bounds__(256) void cbow_loss_kernel(
    const int*   __restrict__ pos_target,     // [B]
    const int*   __restrict__ pos_contexts,   // [B, C]
    const int*   __restrict__ pos_negatives,  // [B, N]
    const float* __restrict__ context_table,  // [VOCAB, 128]
    const float* __restrict__ output_table,   // [VOCAB, 128]
    float*       __restrict__ out)            // [1]
{
    const int tid  = threadIdx.x;
    const int lane = tid & 63;
    const int wave = tid >> 6;          // 0..3
    const int half = lane >> 5;         // 0 or 1
    const int sub  = lane & 31;         // lane within half-wave

    // one batch row per half-wave: 8 rows per 256-thread block
    const int row = blockIdx.x * 8 + wave * 2 + half;

    const float4* ctab = (const float4*)context_table;  // row stride = 32 float4
    const float4* otab = (const float4*)output_table;

    // ---- context sum: mean_contexts[row] (it's a sum in the reference) ----
    float4 acc = make_float4(0.f, 0.f, 0.f, 0.f);
#pragma unroll
    for (int c = 0; c < CTX; ++c) {
        const int idx = pos_contexts[row * CTX + c];
        const float4 v = otab == nullptr ? make_float4(0,0,0,0) : ctab[idx * 32 + sub];
        acc.x += v.x; acc.y += v.y; acc.z += v.z; acc.w += v.w;
    }

    // ---- positive score ----
    const int t = pos_target[row];
    const float4 et = otab[t * 32 + sub];
    float ps = half_wave_dot(acc, et);
    ps = fminf(fmaxf(ps, -10.f), 10.f);
    // objective = -log_sigmoid(ps) = softplus(-ps)
    float loss = log1pf(expf(-ps));

    // ---- negative scores ----
#pragma unroll
    for (int n = 0; n < NEG; ++n) {
        const int idx = pos_negatives[row * NEG + n];
        const float4 ev = otab[idx * 32 + sub];
        float ns = half_wave_dot(acc, ev);
        ns = fminf(fmaxf(ns, -10.f), 10.f);
        // -log_sigmoid(-ns) = softplus(ns)
        loss += log1pf(expf(ns));
    }

    // ---- block reduction: 8 half-wave results -> 1 atomic ----
    __shared__ float sdata[8];
    if (sub == 0) sdata[wave * 2 + half] = loss;
    __syncthreads();
    if (tid == 0) {
        float s = 0.f;
#pragma unroll
        for (int i = 0; i < 8; ++i) s += sdata[i];
        atomicAdd(out, s * (1.0f / (float)BATCH));
    }
}

extern "C" void kernel_launch(void* const* d_in, const int* in_sizes, int n_in,
                              void* d_out, int out_size, void* d_ws, size_t ws_size,
                              hipStream_t stream) {
    const int*   pos_target    = (const int*)d_in[0];
    const int*   pos_contexts  = (const int*)d_in[1];
    const int*   pos_negatives = (const int*)d_in[2];
    const float* context_table = (const float*)d_in[3];
    const float* output_table  = (const float*)d_in[4];
    float* out = (float*)d_out;

    // d_out is poisoned 0xAA before every launch: zero it first (same stream).
    zero_out_kernel<<<1, 1, 0, stream>>>(out);

    const int rows_per_block = 8;  // 4 waves x 2 half-waves
    const int grid = BATCH / rows_per_block;  // 16384 / 8 = 2048
    cbow_loss_kernel<<<grid, 256, 0, stream>>>(
        pos_target, pos_contexts, pos_negatives, context_table, output_table, out);
}

// Round 2
// 151.398 us; speedup vs baseline: 1.1569x; 1.1569x over previous
//
#include <hip/hip_runtime.h>
#include <math.h>

#define VOCAB 100000
#define EMB   128
#define BATCH 16384
#define CTX   20
#define NEG   20
#define NSCORE (NEG + 1)   // target + negatives

__device__ __forceinline__ float dot4(float4 a, float4 b) {
    return fmaf(a.x, b.x, fmaf(a.y, b.y, fmaf(a.z, b.z, a.w * b.w)));
}

// softplus(x) = log(1+exp(x)) via raw v_exp_f32/v_log_f32.
// x is clamped to [-10,10]; abs err ~1e-5, threshold is 0.29 absolute.
__device__ __forceinline__ float fast_softplus(float x) {
    return __logf(1.0f + __expf(x));
}

__global__ __launch_bounds__(256, 4) void cbow_loss_kernel(
    const int*   __restrict__ pos_target,     // [B]
    const int*   __restrict__ pos_contexts,   // [B, C]
    const int*   __restrict__ pos_negatives,  // [B, N]
    const float* __restrict__ context_table,  // [VOCAB, 128]
    const float* __restrict__ output_table,   // [VOCAB, 128]
    float*       __restrict__ out)            // [1]
{
    const int tid  = threadIdx.x;
    const int lane = tid & 63;
    const int wave = tid >> 6;          // 0..3
    const int half = lane >> 5;         // 0 or 1
    const int sub  = lane & 31;         // lane within half-wave

    // one batch row per half-wave: 8 rows per 256-thread block
    const int row = blockIdx.x * 8 + wave * 2 + half;

    const float4* ctab = (const float4*)context_table;  // row stride = 32 float4
    const float4* otab = (const float4*)output_table;

    // ---- context sum (reference sums over the context window) ----
    float4 acc = make_float4(0.f, 0.f, 0.f, 0.f);
    const int cbase = row * CTX;
#pragma unroll
    for (int c = 0; c < CTX; ++c) {
        const int idx = pos_contexts[cbase + c];
        const float4 v = ctab[idx * 32 + sub];
        acc.x += v.x; acc.y += v.y; acc.z += v.z; acc.w += v.w;
    }

    // ---- gather all 21 score indices ----
    int sidx[NSCORE];
    sidx[0] = pos_target[row];
    const int nbase = row * NEG;
#pragma unroll
    for (int n = 0; n < NEG; ++n) sidx[1 + n] = pos_negatives[nbase + n];

    // ---- per-lane partial dots, loads chunked 7-wide so all are in flight
    //      before any dependent use (no swizzle chains between loads) ----
    float part[NSCORE];
#pragma unroll
    for (int g = 0; g < 3; ++g) {
        float4 vb[7];
#pragma unroll
        for (int j = 0; j < 7; ++j) vb[j] = otab[sidx[g * 7 + j] * 32 + sub];
#pragma unroll
        for (int j = 0; j < 7; ++j) part[g * 7 + j] = dot4(acc, vb[j]);
    }

    // ---- 21 independent butterfly reductions, 5 steps each; per step the
    //      21 swizzles are independent and pipeline in the LDS pipe ----
#pragma unroll
    for (int s = 16; s >= 1; s >>= 1) {
#pragma unroll
        for (int n = 0; n < NSCORE; ++n) part[n] += __shfl_xor(part[n], s);
    }

    // ---- loss: softplus(-pos) + sum softplus(neg) ----
    float ps = fminf(fmaxf(part[0], -10.f), 10.f);
    float loss = fast_softplus(-ps);
#pragma unroll
    for (int n = 1; n < NSCORE; ++n) {
        float ns = fminf(fmaxf(part[n], -10.f), 10.f);
        loss += fast_softplus(ns);
    }

    // ---- block reduction: 8 half-wave results -> 1 atomic ----
    __shared__ float sdata[8];
    if (sub == 0) sdata[wave * 2 + half] = loss;
    __syncthreads();
    if (tid == 0) {
        float s = 0.f;
#pragma unroll
        for (int i = 0; i < 8; ++i) s += sdata[i];
        atomicAdd(out, s * (1.0f / (float)BATCH));
    }
}

extern "C" void kernel_launch(void* const* d_in, const int* in_sizes, int n_in,
                              void* d_out, int out_size, void* d_ws, size_t ws_size,
                              hipStream_t stream) {
    const int*   pos_target    = (const int*)d_in[0];
    const int*   pos_contexts  = (const int*)d_in[1];
    const int*   pos_negatives = (const int*)d_in[2];
    const float* context_table = (const float*)d_in[3];
    const float* output_table  = (const float*)d_in[4];
    float* out = (float*)d_out;

    // d_out is poisoned 0xAA before every timed launch; memset node is
    // graph-capturable (no kernel-launch overhead).
    hipMemsetAsync(out, 0, sizeof(float), stream);

    const int rows_per_block = 8;  // 4 waves x 2 half-waves
    const int grid = BATCH / rows_per_block;  // 2048
    cbow_loss_kernel<<<grid, 256, 0, stream>>>(
        pos_target, pos_contexts, pos_negatives, context_table, output_table, out);
}